// Round 1
// baseline (624.335 us; speedup 1.0000x reference)
//
#include <hip/hip_runtime.h>
#include <cmath>

#define NB 8
#define NS 32
#define NP 8
#define NV 8000
#define ND 128
#define CONC 5.0f
#define EPS 1e-8f

// ---------------------------------------------------------------------------
// K1: context vector per batch, normalized.  grid=NB, block=ND(128)
// cn[b][d] = normalize( mean_{s<seg_len} mean_{p<len} embed_w[concepts[b,s,p]][d] )
// ---------------------------------------------------------------------------
__global__ void k_context(const int* __restrict__ concepts,
                          const int* __restrict__ concepts_length,
                          const int* __restrict__ seg_len,
                          const float* __restrict__ embed_w,
                          float* __restrict__ cn) {
    const int b = blockIdx.x;
    const int d = threadIdx.x;           // 0..127
    const int sl = seg_len[b];           // 1..NS
    float acc = 0.0f;
    for (int s = 0; s < sl; ++s) {
        const int len = concepts_length[b * NS + s];
        float sum = 0.0f;
        for (int p = 0; p < len; ++p) {
            const int c = concepts[(b * NS + s) * NP + p];
            sum += embed_w[(size_t)c * ND + d];
        }
        const float denom = (float)(len > 0 ? len : 1);
        acc += sum / denom;
    }
    acc /= (float)sl;

    __shared__ float red[ND];
    red[d] = acc * acc;
    __syncthreads();
    for (int off = ND / 2; off > 0; off >>= 1) {
        if (d < off) red[d] += red[d + off];
        __syncthreads();
    }
    const float nrm = sqrtf(red[0]);
    const float inv = 1.0f / fmaxf(nrm, EPS);
    cn[b * ND + d] = acc * inv;
}

// ---------------------------------------------------------------------------
// K2: cos[b][v] = | cn[b] . normalize(kb[v]) |   grid=NV, block=64 (one wave)
// each lane holds 2 elements of the D=128 row
// ---------------------------------------------------------------------------
__global__ void k_cos(const float* __restrict__ kb,
                      const float* __restrict__ cn,
                      float* __restrict__ cos_bv) {
    const int v = blockIdx.x;
    const int t = threadIdx.x;           // 0..63
    const float kx = kb[(size_t)v * ND + t];
    const float ky = kb[(size_t)v * ND + t + 64];
    float ss = kx * kx + ky * ky;
    for (int off = 32; off > 0; off >>= 1) ss += __shfl_down(ss, off);
    // lane 0 holds full sum
    const float inv = 1.0f / fmaxf(sqrtf(ss), EPS);   // valid on lane 0 only
    for (int b = 0; b < NB; ++b) {
        float dot = kx * cn[b * ND + t] + ky * cn[b * ND + t + 64];
        for (int off = 32; off > 0; off >>= 1) dot += __shfl_down(dot, off);
        if (t == 0) cos_bv[b * NV + v] = fabsf(dot * inv);
    }
}

// ---------------------------------------------------------------------------
// K3: per valid triple (b,s,p): row-normalize edge row, build w, softmax over
// V, GEMV against kb, atomicAdd into out[b,s,:].  grid=NB*NS*NP, block=256
// ---------------------------------------------------------------------------
__global__ __launch_bounds__(256) void k_attn(
        const int* __restrict__ concepts,
        const int* __restrict__ concepts_length,
        const int* __restrict__ seg_len,
        const float* __restrict__ edge,
        const float* __restrict__ aff,
        const float* __restrict__ lam,
        const float* __restrict__ kb,
        const float* __restrict__ cos_bv,
        float* __restrict__ out) {
    const int idx = blockIdx.x;               // b*NS*NP + s*NP + p
    const int b = idx / (NS * NP);
    const int sp = idx % (NS * NP);
    const int s = sp / NP;
    const int p = sp % NP;
    if (s >= seg_len[b]) return;
    const int len = concepts_length[b * NS + s];
    if (p >= len) return;
    const int c = concepts[idx];

    __shared__ float s_row[NV];               // 32000 B
    __shared__ float s_red[256];
    __shared__ float s_part[8 * ND];          // 4096 B

    const int t = threadIdx.x;
    const float* __restrict__ erow = edge + (size_t)c * NV;

    // pass 1: stage edge row to LDS, find row max/min
    float lmax = -INFINITY, lmin = INFINITY;
    for (int u = t; u < NV; u += 256) {
        const float e = erow[u];
        s_row[u] = e;
        lmax = fmaxf(lmax, e);
        lmin = fminf(lmin, e);
    }
    s_red[t] = lmax;
    __syncthreads();
    for (int off = 128; off > 0; off >>= 1) {
        if (t < off) s_red[t] = fmaxf(s_red[t], s_red[t + off]);
        __syncthreads();
    }
    const float rmax = s_red[0];
    __syncthreads();
    s_red[t] = lmin;
    __syncthreads();
    for (int off = 128; off > 0; off >>= 1) {
        if (t < off) s_red[t] = fminf(s_red[t], s_red[t + off]);
        __syncthreads();
    }
    const float rmin = s_red[0];
    __syncthreads();
    const float rng = rmax - rmin;
    const float inv_rng = 1.0f / (rng + (rng == 0.0f ? 1.0f : 0.0f));

    // pass 2: w = lam*em*cos + (1-lam)*(em>0)*aff, scaled; track max
    const float* __restrict__ cosb = cos_bv + b * NV;
    float wmax = -INFINITY;
    for (int u = t; u < NV; u += 256) {
        const float e = s_row[u] * inv_rng;
        const float l = lam[u];
        const float flag = (e > 0.0f) ? 1.0f : 0.0f;
        const float w = (l * e * cosb[u] + (1.0f - l) * flag * aff[u]) * CONC;
        s_row[u] = w;                          // own slot, no race
        wmax = fmaxf(wmax, w);
    }
    s_red[t] = wmax;
    __syncthreads();
    for (int off = 128; off > 0; off >>= 1) {
        if (t < off) s_red[t] = fmaxf(s_red[t], s_red[t + off]);
        __syncthreads();
    }
    const float gmax = s_red[0];
    __syncthreads();

    // pass 3: exponentiate, accumulate sum
    float lsum = 0.0f;
    for (int u = t; u < NV; u += 256) {
        const float pe = expf(s_row[u] - gmax);
        s_row[u] = pe;
        lsum += pe;
    }
    s_red[t] = lsum;
    __syncthreads();
    for (int off = 128; off > 0; off >>= 1) {
        if (t < off) s_red[t] += s_red[t + off];
        __syncthreads();
    }
    const float invsum = 1.0f / s_red[0];
    __syncthreads();

    // GEMV: out_d = sum_u p[u] * kb[u][d].  256 thr = 32 d-groups x 8 u-groups
    const int dg = (t & 31) * 4;
    const int ug = t >> 5;                    // 0..7
    float4 acc = make_float4(0.f, 0.f, 0.f, 0.f);
    for (int u = ug; u < NV; u += 8) {        // NV/8 = 1000 iters exactly
        const float pv = s_row[u];
        const float4 kv = *reinterpret_cast<const float4*>(kb + (size_t)u * ND + dg);
        acc.x += pv * kv.x;
        acc.y += pv * kv.y;
        acc.z += pv * kv.z;
        acc.w += pv * kv.w;
    }
    *reinterpret_cast<float4*>(&s_part[ug * ND + dg]) = acc;
    __syncthreads();

    const float scale = invsum / (float)len;  // len >= 1 here
    if (t < ND) {
        float sum = 0.0f;
        for (int g = 0; g < 8; ++g) sum += s_part[g * ND + t];
        atomicAdd(&out[((size_t)(b * NS + s)) * ND + t], sum * scale);
    }
}

extern "C" void kernel_launch(void* const* d_in, const int* in_sizes, int n_in,
                              void* d_out, int out_size, void* d_ws, size_t ws_size,
                              hipStream_t stream) {
    const int*   concepts        = (const int*)d_in[0];
    const int*   concepts_length = (const int*)d_in[1];
    const int*   seg_len         = (const int*)d_in[2];
    const float* embed_w         = (const float*)d_in[3];
    const float* embed_kb_w      = (const float*)d_in[4];
    const float* edge_matrix     = (const float*)d_in[5];
    const float* affectiveness   = (const float*)d_in[6];
    const float* lam             = (const float*)d_in[7];
    float* out = (float*)d_out;

    float* ws = (float*)d_ws;
    float* cn     = ws;                 // NB*ND   = 1024 floats
    float* cos_bv = ws + NB * ND;       // NB*NV   = 64000 floats

    // output must be zero (harness poisons with 0xAA)
    hipMemsetAsync(out, 0, (size_t)out_size * sizeof(float), stream);

    k_context<<<NB, ND, 0, stream>>>(concepts, concepts_length, seg_len,
                                     embed_w, cn);
    k_cos<<<NV, 64, 0, stream>>>(embed_kb_w, cn, cos_bv);
    k_attn<<<NB * NS * NP, 256, 0, stream>>>(concepts, concepts_length, seg_len,
                                             edge_matrix, affectiveness, lam,
                                             embed_kb_w, cos_bv, out);
}

// Round 2
// 592.123 us; speedup vs baseline: 1.0544x; 1.0544x over previous
//
#include <hip/hip_runtime.h>
#include <cmath>

#define NB 8
#define NS 32
#define NP 8
#define NV 8000
#define ND 128
#define CONC 5.0f
#define EPS 1e-8f

#define TROWS 8          // slots per k_B tile
#define USPLIT 5         // u-dimension splits (8000 = 5*1600)
#define URANGE 1600
#define UCHUNK 64
#define NCHUNK (URANGE / UCHUNK)   // 25
#define MAXSLOTS (NB * NS * NP)    // 2048

// ---- workspace layout (4-byte units) ----
// [0]        counter (int)
// [16]       meta_c   [2048] int
// [2064]     meta_out [2048] int
// [4112]     f_irng   [2048]
// [6160]     f_gmax   [2048]
// [8208]     f_scale  [2048]
// [10256]    cn       [NB*ND = 1024]
// [11280]    cos_bv   [NB*NV = 64000]
// [75280]    mean_j   [NB*NS*ND = 32768]
#define WS_COUNTER 0
#define WS_META_C  16
#define WS_META_O  2064
#define WS_IRNG    4112
#define WS_GMAX    6160
#define WS_SCALE   8208
#define WS_CN      10256
#define WS_COS     11280
#define WS_MEANJ   75280

// ---------------------------------------------------------------------------
// k_mean: per (b,s), ragged mean over P.  grid=NB*NS, block=ND
// ---------------------------------------------------------------------------
__global__ void k_mean(const int* __restrict__ concepts,
                       const int* __restrict__ concepts_length,
                       const float* __restrict__ embed_w,
                       float* __restrict__ mean_j) {
    const int bs = blockIdx.x;
    const int d = threadIdx.x;
    const int len = concepts_length[bs];
    float sum = 0.0f;
    for (int p = 0; p < len; ++p) {
        const int c = concepts[bs * NP + p];
        sum += embed_w[(size_t)c * ND + d];
    }
    mean_j[(size_t)bs * ND + d] = sum / (float)(len > 0 ? len : 1);
}

// ---------------------------------------------------------------------------
// k_ctx2: per b, mean over valid segments + normalize.  grid=NB, block=ND
// ---------------------------------------------------------------------------
__global__ void k_ctx2(const int* __restrict__ seg_len,
                       const float* __restrict__ mean_j,
                       float* __restrict__ cn) {
    const int b = blockIdx.x;
    const int d = threadIdx.x;
    const int sl = seg_len[b];
    float acc = 0.0f;
    for (int s = 0; s < sl; ++s) acc += mean_j[(size_t)(b * NS + s) * ND + d];
    acc /= (float)sl;
    float ss = acc * acc;
    #pragma unroll
    for (int m = 1; m < 64; m <<= 1) ss += __shfl_xor(ss, m);
    __shared__ float sred[2];
    if ((d & 63) == 0) sred[d >> 6] = ss;
    __syncthreads();
    const float tot = sred[0] + sred[1];
    cn[b * ND + d] = acc / fmaxf(sqrtf(tot), EPS);
}

// ---------------------------------------------------------------------------
// k_cos: cos[b][v] = |cn[b] . normalize(kb[v])|.  grid=NV/8, block=256
// 8 rows per block, 32 lanes per row, float4 per lane.
// ---------------------------------------------------------------------------
__global__ __launch_bounds__(256) void k_cos(const float* __restrict__ kb,
                                             const float* __restrict__ cn,
                                             float* __restrict__ cos_bv) {
    __shared__ float s_cn[NB * ND];           // 4 KB
    const int t = threadIdx.x;
    for (int i = t; i < NB * ND; i += 256) s_cn[i] = cn[i];
    __syncthreads();

    const int v = blockIdx.x * 8 + (t >> 5);
    const int l = t & 31;
    const float4 kv = *reinterpret_cast<const float4*>(kb + (size_t)v * ND + (l << 2));
    float ss = kv.x * kv.x + kv.y * kv.y + kv.z * kv.z + kv.w * kv.w;
    #pragma unroll
    for (int m = 1; m < 32; m <<= 1) ss += __shfl_xor(ss, m);
    const float inv = 1.0f / fmaxf(sqrtf(ss), EPS);
    #pragma unroll
    for (int b = 0; b < NB; ++b) {
        const float4 cv = *reinterpret_cast<const float4*>(&s_cn[b * ND + (l << 2)]);
        float dot = kv.x * cv.x + kv.y * cv.y + kv.z * cv.z + kv.w * cv.w;
        #pragma unroll
        for (int m = 1; m < 32; m <<= 1) dot += __shfl_xor(dot, m);
        if (l == 0) cos_bv[b * NV + v] = fabsf(dot * inv);
    }
}

// ---------------------------------------------------------------------------
// k_A: per valid triple, softmax statistics (inv_rng, gmax, scale) + compact
// slot list.  grid=2048, block=256.  Edge row held in registers (32/thread).
// ---------------------------------------------------------------------------
__global__ __launch_bounds__(256) void k_A(
        const int* __restrict__ concepts,
        const int* __restrict__ concepts_length,
        const int* __restrict__ seg_len,
        const float* __restrict__ edge,
        const float* __restrict__ aff,
        const float* __restrict__ lam,
        const float* __restrict__ cos_bv,
        int* __restrict__ counter,
        int* __restrict__ meta_c, int* __restrict__ meta_out,
        float* __restrict__ f_irng, float* __restrict__ f_gmax,
        float* __restrict__ f_scale) {
    const int idx = blockIdx.x;
    const int b = idx >> 8;
    const int s = (idx >> 3) & 31;
    const int p = idx & 7;
    if (s >= seg_len[b]) return;
    const int len = concepts_length[b * NS + s];
    if (p >= len) return;
    const int c = concepts[idx];

    const int t = threadIdx.x;
    const float* __restrict__ erow = edge + (size_t)c * NV;
    float ev[32];
    float lmax = -INFINITY, lmin = INFINITY;
    #pragma unroll
    for (int k = 0; k < 31; ++k) {
        const float e = erow[t + (k << 8)];
        ev[k] = e;
        lmax = fmaxf(lmax, e);
        lmin = fminf(lmin, e);
    }
    if (t < 64) {                              // tail: u = 7936 + t
        const float e = erow[7936 + t];
        ev[31] = e;
        lmax = fmaxf(lmax, e);
        lmin = fminf(lmin, e);
    }
    // block reduce min+max
    #pragma unroll
    for (int m = 1; m < 64; m <<= 1) {
        lmax = fmaxf(lmax, __shfl_xor(lmax, m));
        lmin = fminf(lmin, __shfl_xor(lmin, m));
    }
    __shared__ float s_min[4], s_max[4], s_wm[4], s_sum[4];
    if ((t & 63) == 0) { s_min[t >> 6] = lmin; s_max[t >> 6] = lmax; }
    __syncthreads();
    const float rmin = fminf(fminf(s_min[0], s_min[1]), fminf(s_min[2], s_min[3]));
    const float rmax = fmaxf(fmaxf(s_max[0], s_max[1]), fmaxf(s_max[2], s_max[3]));
    const float rng = rmax - rmin;
    const float inv_rng = 1.0f / (rng + (rng == 0.0f ? 1.0f : 0.0f));

    // pass 2: w, track max
    const float* __restrict__ cosb = cos_bv + b * NV;
    float wmax = -INFINITY;
    #pragma unroll
    for (int k = 0; k < 31; ++k) {
        const int u = t + (k << 8);
        const float e = ev[k] * inv_rng;
        const float lm = lam[u];
        const float w = (lm * e * cosb[u] + (1.0f - lm) * ((e > 0.0f) ? 1.0f : 0.0f) * aff[u]) * CONC;
        ev[k] = w;
        wmax = fmaxf(wmax, w);
    }
    if (t < 64) {
        const int u = 7936 + t;
        const float e = ev[31] * inv_rng;
        const float lm = lam[u];
        const float w = (lm * e * cosb[u] + (1.0f - lm) * ((e > 0.0f) ? 1.0f : 0.0f) * aff[u]) * CONC;
        ev[31] = w;
        wmax = fmaxf(wmax, w);
    }
    #pragma unroll
    for (int m = 1; m < 64; m <<= 1) wmax = fmaxf(wmax, __shfl_xor(wmax, m));
    if ((t & 63) == 0) s_wm[t >> 6] = wmax;
    __syncthreads();
    const float gmax = fmaxf(fmaxf(s_wm[0], s_wm[1]), fmaxf(s_wm[2], s_wm[3]));

    // pass 3: sum of exp
    float lsum = 0.0f;
    #pragma unroll
    for (int k = 0; k < 31; ++k) lsum += expf(ev[k] - gmax);
    if (t < 64) lsum += expf(ev[31] - gmax);
    #pragma unroll
    for (int m = 1; m < 64; m <<= 1) lsum += __shfl_xor(lsum, m);
    if ((t & 63) == 0) s_sum[t >> 6] = lsum;
    __syncthreads();
    if (t == 0) {
        const float total = s_sum[0] + s_sum[1] + s_sum[2] + s_sum[3];
        const int slot = atomicAdd(counter, 1);
        meta_c[slot] = c;
        meta_out[slot] = b * NS + s;
        f_irng[slot] = inv_rng;
        f_gmax[slot] = gmax;
        f_scale[slot] = 1.0f / (total * (float)len);
    }
}

// ---------------------------------------------------------------------------
// k_B: batched GEMV.  grid=(MAXSLOTS/TROWS, USPLIT), block=256.
// 8 slots share one kb stream; p recomputed per 64-u chunk into LDS.
// ---------------------------------------------------------------------------
__global__ __launch_bounds__(256) void k_B(
        const float* __restrict__ edge,
        const float* __restrict__ aff,
        const float* __restrict__ lam,
        const float* __restrict__ kb,
        const float* __restrict__ cos_bv,
        const int* __restrict__ counter,
        const int* __restrict__ meta_c, const int* __restrict__ meta_out,
        const float* __restrict__ f_irng, const float* __restrict__ f_gmax,
        const float* __restrict__ f_scale,
        float* __restrict__ out) {
    const int count = counter[0];
    const int tile = blockIdx.x;
    if (tile * TROWS >= count) return;

    const int t = threadIdx.x;
    const int i = t >> 5;                     // row in tile, 0..7
    const int l = t & 31;                     // lane in row

    __shared__ int s_c[TROWS], s_o[TROWS], s_b[TROWS];
    __shared__ float s_irng[TROWS], s_gmax[TROWS], s_scale[TROWS];
    __shared__ float s_p[TROWS * UCHUNK];     // 2 KB

    if (t < TROWS) {
        const int slot = tile * TROWS + t;
        if (slot < count) {
            const int c = meta_c[slot];
            const int o = meta_out[slot];
            s_c[t] = c; s_o[t] = o; s_b[t] = o >> 5;
            s_irng[t] = f_irng[slot];
            s_gmax[t] = f_gmax[slot];
            s_scale[t] = f_scale[slot];
        } else {
            s_c[t] = -1; s_o[t] = 0; s_b[t] = 0;
            s_irng[t] = 0.0f; s_gmax[t] = 0.0f; s_scale[t] = 0.0f;
        }
    }
    __syncthreads();

    const int u0 = blockIdx.y * URANGE;
    const bool valid = (tile * TROWS + i) < count;

    // indices for p staging: thread t computes p for (r, uu) and (r, uu+1)
    const int ii = t << 1;
    const int pr = ii >> 6;
    const int puu = ii & 63;

    float4 acc = make_float4(0.f, 0.f, 0.f, 0.f);

    for (int ch = 0; ch < NCHUNK; ++ch) {
        const int uc = u0 + ch * UCHUNK;
        // ---- stage p[8][64] ----
        const int cc = s_c[pr];
        float2 pv = make_float2(0.f, 0.f);
        if (cc >= 0) {
            const int u = uc + puu;
            const float ir = s_irng[pr];
            const float gm = s_gmax[pr];
            const float2 e2 = *reinterpret_cast<const float2*>(edge + (size_t)cc * NV + u);
            const float2 l2 = *reinterpret_cast<const float2*>(lam + u);
            const float2 a2 = *reinterpret_cast<const float2*>(aff + u);
            const float2 c2 = *reinterpret_cast<const float2*>(cos_bv + (size_t)s_b[pr] * NV + u);
            const float e0 = e2.x * ir, e1 = e2.y * ir;
            const float w0 = (l2.x * e0 * c2.x + (1.0f - l2.x) * ((e0 > 0.0f) ? 1.0f : 0.0f) * a2.x) * CONC;
            const float w1 = (l2.y * e1 * c2.y + (1.0f - l2.y) * ((e1 > 0.0f) ? 1.0f : 0.0f) * a2.y) * CONC;
            pv.x = expf(w0 - gm);
            pv.y = expf(w1 - gm);
        }
        *reinterpret_cast<float2*>(&s_p[ii]) = pv;
        __syncthreads();

        // ---- accumulate: acc += p[i][uu] * kb[uc+uu][l*4 .. +4] ----
        const float* __restrict__ kbase = kb + (size_t)uc * ND + (l << 2);
        const float* __restrict__ prow = &s_p[i << 6];
        #pragma unroll 16
        for (int uu = 0; uu < UCHUNK; ++uu) {
            const float pvv = prow[uu];
            const float4 kv = *reinterpret_cast<const float4*>(kbase + (size_t)uu * ND);
            acc.x = fmaf(pvv, kv.x, acc.x);
            acc.y = fmaf(pvv, kv.y, acc.y);
            acc.z = fmaf(pvv, kv.z, acc.z);
            acc.w = fmaf(pvv, kv.w, acc.w);
        }
        __syncthreads();
    }

    if (valid) {
        const float sc = s_scale[i];
        float* o = out + (size_t)s_o[i] * ND + (l << 2);
        atomicAdd(o + 0, acc.x * sc);
        atomicAdd(o + 1, acc.y * sc);
        atomicAdd(o + 2, acc.z * sc);
        atomicAdd(o + 3, acc.w * sc);
    }
}

extern "C" void kernel_launch(void* const* d_in, const int* in_sizes, int n_in,
                              void* d_out, int out_size, void* d_ws, size_t ws_size,
                              hipStream_t stream) {
    const int*   concepts        = (const int*)d_in[0];
    const int*   concepts_length = (const int*)d_in[1];
    const int*   seg_len         = (const int*)d_in[2];
    const float* embed_w         = (const float*)d_in[3];
    const float* embed_kb_w      = (const float*)d_in[4];
    const float* edge_matrix     = (const float*)d_in[5];
    const float* affectiveness   = (const float*)d_in[6];
    const float* lam             = (const float*)d_in[7];
    float* out = (float*)d_out;

    float* wsf = (float*)d_ws;
    int*   wsi = (int*)d_ws;
    int*   counter  = wsi + WS_COUNTER;
    int*   meta_c   = wsi + WS_META_C;
    int*   meta_out = wsi + WS_META_O;
    float* f_irng   = wsf + WS_IRNG;
    float* f_gmax   = wsf + WS_GMAX;
    float* f_scale  = wsf + WS_SCALE;
    float* cn       = wsf + WS_CN;
    float* cos_bv   = wsf + WS_COS;
    float* mean_j   = wsf + WS_MEANJ;

    hipMemsetAsync(out, 0, (size_t)out_size * sizeof(float), stream);
    hipMemsetAsync(counter, 0, 64, stream);

    k_mean<<<NB * NS, ND, 0, stream>>>(concepts, concepts_length, embed_w, mean_j);
    k_ctx2<<<NB, ND, 0, stream>>>(seg_len, mean_j, cn);
    k_cos<<<NV / 8, 256, 0, stream>>>(embed_kb_w, cn, cos_bv);
    k_A<<<MAXSLOTS, 256, 0, stream>>>(concepts, concepts_length, seg_len,
                                      edge_matrix, affectiveness, lam, cos_bv,
                                      counter, meta_c, meta_out,
                                      f_irng, f_gmax, f_scale);
    dim3 gB(MAXSLOTS / TROWS, USPLIT, 1);
    k_B<<<gB, 256, 0, stream>>>(edge_matrix, affectiveness, lam, embed_kb_w,
                                cos_bv, counter, meta_c, meta_out,
                                f_irng, f_gmax, f_scale, out);
}

// Round 3
// 412.212 us; speedup vs baseline: 1.5146x; 1.4365x over previous
//
#include <hip/hip_runtime.h>
#include <cmath>

#define NB 8
#define NS 32
#define NP 8
#define NV 8000
#define ND 128
#define CONC 5.0f
#define EPS 1e-8f

#define TROWS 8            // slots per k_B tile
#define USPLIT 25          // u-dimension splits: 8000 = 25*320
#define URANGE 320
#define UCHUNK 64
#define NCHUNK (URANGE / UCHUNK)   // 5
#define MAXSLOTS (NB * NS * NP)    // 2048

// ---- workspace layout (4-byte units) ----
#define WS_COUNTER 0
#define WS_META_C  16
#define WS_META_O  2064
#define WS_IRNG    4112
#define WS_GMAX    6160
#define WS_SCALE   8208
#define WS_CN      10256
#define WS_COS     11280
#define WS_MEANJ   75280

// ---------------------------------------------------------------------------
// k_mean: per (b,s), ragged mean over P.  grid=NB*NS, block=ND
// ---------------------------------------------------------------------------
__global__ void k_mean(const int* __restrict__ concepts,
                       const int* __restrict__ concepts_length,
                       const float* __restrict__ embed_w,
                       float* __restrict__ mean_j) {
    const int bs = blockIdx.x;
    const int d = threadIdx.x;
    const int len = concepts_length[bs];
    float sum = 0.0f;
    for (int p = 0; p < len; ++p) {
        const int c = concepts[bs * NP + p];
        sum += embed_w[(size_t)c * ND + d];
    }
    mean_j[(size_t)bs * ND + d] = sum / (float)(len > 0 ? len : 1);
}

// ---------------------------------------------------------------------------
// k_ctx2: per b, mean over valid segments + normalize.  grid=NB, block=ND
// ---------------------------------------------------------------------------
__global__ void k_ctx2(const int* __restrict__ seg_len,
                       const float* __restrict__ mean_j,
                       float* __restrict__ cn) {
    const int b = blockIdx.x;
    const int d = threadIdx.x;
    const int sl = seg_len[b];
    float acc = 0.0f;
    for (int s = 0; s < sl; ++s) acc += mean_j[(size_t)(b * NS + s) * ND + d];
    acc /= (float)sl;
    float ss = acc * acc;
    #pragma unroll
    for (int m = 1; m < 64; m <<= 1) ss += __shfl_xor(ss, m);
    __shared__ float sred[2];
    if ((d & 63) == 0) sred[d >> 6] = ss;
    __syncthreads();
    const float tot = sred[0] + sred[1];
    cn[b * ND + d] = acc / fmaxf(sqrtf(tot), EPS);
}

// ---------------------------------------------------------------------------
// k_cos: cos[b][v] = |cn[b] . normalize(kb[v])|.  grid=NV/8, block=256
// ---------------------------------------------------------------------------
__global__ __launch_bounds__(256) void k_cos(const float* __restrict__ kb,
                                             const float* __restrict__ cn,
                                             float* __restrict__ cos_bv) {
    __shared__ float s_cn[NB * ND];
    const int t = threadIdx.x;
    for (int i = t; i < NB * ND; i += 256) s_cn[i] = cn[i];
    __syncthreads();

    const int v = blockIdx.x * 8 + (t >> 5);
    const int l = t & 31;
    const float4 kv = *reinterpret_cast<const float4*>(kb + (size_t)v * ND + (l << 2));
    float ss = kv.x * kv.x + kv.y * kv.y + kv.z * kv.z + kv.w * kv.w;
    #pragma unroll
    for (int m = 1; m < 32; m <<= 1) ss += __shfl_xor(ss, m);
    const float inv = 1.0f / fmaxf(sqrtf(ss), EPS);
    #pragma unroll
    for (int b = 0; b < NB; ++b) {
        const float4 cv = *reinterpret_cast<const float4*>(&s_cn[b * ND + (l << 2)]);
        float dot = kv.x * cv.x + kv.y * cv.y + kv.z * cv.z + kv.w * cv.w;
        #pragma unroll
        for (int m = 1; m < 32; m <<= 1) dot += __shfl_xor(dot, m);
        if (l == 0) cos_bv[b * NV + v] = fabsf(dot * inv);
    }
}

// ---------------------------------------------------------------------------
// k_A: per valid triple, softmax statistics + compact slot list.
// grid=2048, block=256.  Edge row in registers as float4[8] (2048 f4 slots,
// 2000 valid).
// ---------------------------------------------------------------------------
__global__ __launch_bounds__(256) void k_A(
        const int* __restrict__ concepts,
        const int* __restrict__ concepts_length,
        const int* __restrict__ seg_len,
        const float* __restrict__ edge,
        const float* __restrict__ aff,
        const float* __restrict__ lam,
        const float* __restrict__ cos_bv,
        int* __restrict__ counter,
        int* __restrict__ meta_c, int* __restrict__ meta_out,
        float* __restrict__ f_irng, float* __restrict__ f_gmax,
        float* __restrict__ f_scale) {
    const int idx = blockIdx.x;
    const int b = idx >> 8;
    const int s = (idx >> 3) & 31;
    const int p = idx & 7;
    if (s >= seg_len[b]) return;
    const int len = concepts_length[b * NS + s];
    if (p >= len) return;
    const int c = concepts[idx];

    const int t = threadIdx.x;
    const float* __restrict__ erow = edge + (size_t)c * NV;
    float4 ev[8];
    float lmax = -INFINITY, lmin = INFINITY;
    #pragma unroll
    for (int k = 0; k < 8; ++k) {
        const int f = t + (k << 8);            // float4 index, valid < 2000
        if (f < 2000) {
            const float4 e = *reinterpret_cast<const float4*>(erow + (f << 2));
            ev[k] = e;
            lmax = fmaxf(lmax, fmaxf(fmaxf(e.x, e.y), fmaxf(e.z, e.w)));
            lmin = fminf(lmin, fminf(fminf(e.x, e.y), fminf(e.z, e.w)));
        }
    }
    #pragma unroll
    for (int m = 1; m < 64; m <<= 1) {
        lmax = fmaxf(lmax, __shfl_xor(lmax, m));
        lmin = fminf(lmin, __shfl_xor(lmin, m));
    }
    __shared__ float s_min[4], s_max[4], s_wm[4], s_sum[4];
    if ((t & 63) == 0) { s_min[t >> 6] = lmin; s_max[t >> 6] = lmax; }
    __syncthreads();
    const float rmin = fminf(fminf(s_min[0], s_min[1]), fminf(s_min[2], s_min[3]));
    const float rmax = fmaxf(fmaxf(s_max[0], s_max[1]), fmaxf(s_max[2], s_max[3]));
    const float rng = rmax - rmin;
    const float inv_rng = 1.0f / (rng + (rng == 0.0f ? 1.0f : 0.0f));

    const float* __restrict__ cosb = cos_bv + b * NV;
    float wmax = -INFINITY;
    #pragma unroll
    for (int k = 0; k < 8; ++k) {
        const int f = t + (k << 8);
        if (f < 2000) {
            const int u = f << 2;
            const float4 l4 = *reinterpret_cast<const float4*>(lam + u);
            const float4 a4 = *reinterpret_cast<const float4*>(aff + u);
            const float4 c4 = *reinterpret_cast<const float4*>(cosb + u);
            float4 e = ev[k];
            e.x *= inv_rng; e.y *= inv_rng; e.z *= inv_rng; e.w *= inv_rng;
            float4 w;
            w.x = (l4.x * e.x * c4.x + (1.0f - l4.x) * ((e.x > 0.0f) ? 1.0f : 0.0f) * a4.x) * CONC;
            w.y = (l4.y * e.y * c4.y + (1.0f - l4.y) * ((e.y > 0.0f) ? 1.0f : 0.0f) * a4.y) * CONC;
            w.z = (l4.z * e.z * c4.z + (1.0f - l4.z) * ((e.z > 0.0f) ? 1.0f : 0.0f) * a4.z) * CONC;
            w.w = (l4.w * e.w * c4.w + (1.0f - l4.w) * ((e.w > 0.0f) ? 1.0f : 0.0f) * a4.w) * CONC;
            ev[k] = w;
            wmax = fmaxf(wmax, fmaxf(fmaxf(w.x, w.y), fmaxf(w.z, w.w)));
        } else {
            ev[k] = make_float4(-INFINITY, -INFINITY, -INFINITY, -INFINITY);
        }
    }
    #pragma unroll
    for (int m = 1; m < 64; m <<= 1) wmax = fmaxf(wmax, __shfl_xor(wmax, m));
    if ((t & 63) == 0) s_wm[t >> 6] = wmax;
    __syncthreads();
    const float gmax = fmaxf(fmaxf(s_wm[0], s_wm[1]), fmaxf(s_wm[2], s_wm[3]));

    float lsum = 0.0f;
    #pragma unroll
    for (int k = 0; k < 8; ++k) {
        lsum += __expf(ev[k].x - gmax);
        lsum += __expf(ev[k].y - gmax);
        lsum += __expf(ev[k].z - gmax);
        lsum += __expf(ev[k].w - gmax);
    }
    #pragma unroll
    for (int m = 1; m < 64; m <<= 1) lsum += __shfl_xor(lsum, m);
    if ((t & 63) == 0) s_sum[t >> 6] = lsum;
    __syncthreads();
    if (t == 0) {
        const float total = s_sum[0] + s_sum[1] + s_sum[2] + s_sum[3];
        const int slot = atomicAdd(counter, 1);
        meta_c[slot] = c;
        meta_out[slot] = b * NS + s;
        f_irng[slot] = inv_rng;
        f_gmax[slot] = gmax;
        f_scale[slot] = 1.0f / (total * (float)len);
    }
}

// ---------------------------------------------------------------------------
// k_B: batched GEMV with register-level kb reuse.
// grid=(MAXSLOTS/TROWS, USPLIT), block=256.
// thread t: ug = t&7 (u-group, lane bits 0-2), l = t>>3 (d-group 0..31).
// Each thread: load kb[u][4d] once, FMA into 8 slot-accumulators.
// Cross-ug reduction via shfl_xor butterfly (lane bits 0-2).
// ---------------------------------------------------------------------------
__global__ __launch_bounds__(256) void k_B(
        const float* __restrict__ edge,
        const float* __restrict__ aff,
        const float* __restrict__ lam,
        const float* __restrict__ kb,
        const float* __restrict__ cos_bv,
        const int* __restrict__ counter,
        const int* __restrict__ meta_c, const int* __restrict__ meta_out,
        const float* __restrict__ f_irng, const float* __restrict__ f_gmax,
        const float* __restrict__ f_scale,
        float* __restrict__ out) {
    const int count = counter[0];
    const int tile = blockIdx.x;
    if (tile * TROWS >= count) return;

    const int t = threadIdx.x;
    const int ug = t & 7;
    const int l = t >> 3;

    __shared__ int s_c[TROWS], s_o[TROWS], s_b[TROWS];
    __shared__ float s_irng[TROWS], s_gmax[TROWS], s_scale[TROWS];
    __shared__ __align__(16) float s_p[UCHUNK * TROWS];  // [uu][slot], 2 KB

    if (t < TROWS) {
        const int slot = tile * TROWS + t;
        if (slot < count) {
            const int c = meta_c[slot];
            const int o = meta_out[slot];
            s_c[t] = c; s_o[t] = o; s_b[t] = o >> 5;
            s_irng[t] = f_irng[slot];
            s_gmax[t] = f_gmax[slot];
            s_scale[t] = f_scale[slot];
        } else {
            s_c[t] = -1; s_o[t] = 0; s_b[t] = 0;
            s_irng[t] = 0.0f; s_gmax[t] = 0.0f; s_scale[t] = 0.0f;
        }
    }
    __syncthreads();

    const int u0 = blockIdx.y * URANGE;

    float4 acc[TROWS];
    #pragma unroll
    for (int j = 0; j < TROWS; ++j) acc[j] = make_float4(0.f, 0.f, 0.f, 0.f);

    for (int ch = 0; ch < NCHUNK; ++ch) {
        const int uc = u0 + ch * UCHUNK;

        // ---- stage p[uu][slot]: 512 values, 2 per thread ----
        #pragma unroll
        for (int rep = 0; rep < 2; ++rep) {
            const int ii = t + (rep << 8);
            const int slot = ii & 7;
            const int uu = ii >> 3;
            const int cc = s_c[slot];
            float pv = 0.0f;
            if (cc >= 0) {
                const int u = uc + uu;
                const float e = edge[(size_t)cc * NV + u] * s_irng[slot];
                const float lm = lam[u];
                const float w = (lm * e * cos_bv[(size_t)s_b[slot] * NV + u]
                                 + (1.0f - lm) * ((e > 0.0f) ? 1.0f : 0.0f) * aff[u]) * CONC;
                pv = __expf(w - s_gmax[slot]);
            }
            s_p[ii] = pv;
        }
        __syncthreads();

        // ---- compute: 8 u per thread, kb loaded once, used by 8 slots ----
        #pragma unroll
        for (int r = 0; r < 8; ++r) {
            const int uu = ug + (r << 3);
            const float4 kv = *reinterpret_cast<const float4*>(
                kb + (size_t)(uc + uu) * ND + (l << 2));
            const float4 p0 = *reinterpret_cast<const float4*>(&s_p[uu * TROWS]);
            const float4 p1 = *reinterpret_cast<const float4*>(&s_p[uu * TROWS + 4]);
            acc[0].x = fmaf(p0.x, kv.x, acc[0].x); acc[0].y = fmaf(p0.x, kv.y, acc[0].y);
            acc[0].z = fmaf(p0.x, kv.z, acc[0].z); acc[0].w = fmaf(p0.x, kv.w, acc[0].w);
            acc[1].x = fmaf(p0.y, kv.x, acc[1].x); acc[1].y = fmaf(p0.y, kv.y, acc[1].y);
            acc[1].z = fmaf(p0.y, kv.z, acc[1].z); acc[1].w = fmaf(p0.y, kv.w, acc[1].w);
            acc[2].x = fmaf(p0.z, kv.x, acc[2].x); acc[2].y = fmaf(p0.z, kv.y, acc[2].y);
            acc[2].z = fmaf(p0.z, kv.z, acc[2].z); acc[2].w = fmaf(p0.z, kv.w, acc[2].w);
            acc[3].x = fmaf(p0.w, kv.x, acc[3].x); acc[3].y = fmaf(p0.w, kv.y, acc[3].y);
            acc[3].z = fmaf(p0.w, kv.z, acc[3].z); acc[3].w = fmaf(p0.w, kv.w, acc[3].w);
            acc[4].x = fmaf(p1.x, kv.x, acc[4].x); acc[4].y = fmaf(p1.x, kv.y, acc[4].y);
            acc[4].z = fmaf(p1.x, kv.z, acc[4].z); acc[4].w = fmaf(p1.x, kv.w, acc[4].w);
            acc[5].x = fmaf(p1.y, kv.x, acc[5].x); acc[5].y = fmaf(p1.y, kv.y, acc[5].y);
            acc[5].z = fmaf(p1.y, kv.z, acc[5].z); acc[5].w = fmaf(p1.y, kv.w, acc[5].w);
            acc[6].x = fmaf(p1.z, kv.x, acc[6].x); acc[6].y = fmaf(p1.z, kv.y, acc[6].y);
            acc[6].z = fmaf(p1.z, kv.z, acc[6].z); acc[6].w = fmaf(p1.z, kv.w, acc[6].w);
            acc[7].x = fmaf(p1.w, kv.x, acc[7].x); acc[7].y = fmaf(p1.w, kv.y, acc[7].y);
            acc[7].z = fmaf(p1.w, kv.z, acc[7].z); acc[7].w = fmaf(p1.w, kv.w, acc[7].w);
        }
        __syncthreads();
    }

    // ---- butterfly reduce over ug (lane bits 0-2), each ug lane keeps slot=ug
    float4 res = make_float4(0.f, 0.f, 0.f, 0.f);
    #pragma unroll
    for (int j = 0; j < TROWS; ++j) {
        float4 a = acc[j];
        #pragma unroll
        for (int m = 1; m <= 4; m <<= 1) {
            a.x += __shfl_xor(a.x, m);
            a.y += __shfl_xor(a.y, m);
            a.z += __shfl_xor(a.z, m);
            a.w += __shfl_xor(a.w, m);
        }
        if (ug == j) res = a;
    }

    const int myslot = tile * TROWS + ug;
    if (myslot < count && s_c[ug] >= 0) {
        const float sc = s_scale[ug];
        float* o = out + (size_t)s_o[ug] * ND + (l << 2);
        atomicAdd(o + 0, res.x * sc);
        atomicAdd(o + 1, res.y * sc);
        atomicAdd(o + 2, res.z * sc);
        atomicAdd(o + 3, res.w * sc);
    }
}

extern "C" void kernel_launch(void* const* d_in, const int* in_sizes, int n_in,
                              void* d_out, int out_size, void* d_ws, size_t ws_size,
                              hipStream_t stream) {
    const int*   concepts        = (const int*)d_in[0];
    const int*   concepts_length = (const int*)d_in[1];
    const int*   seg_len         = (const int*)d_in[2];
    const float* embed_w         = (const float*)d_in[3];
    const float* embed_kb_w      = (const float*)d_in[4];
    const float* edge_matrix     = (const float*)d_in[5];
    const float* affectiveness   = (const float*)d_in[6];
    const float* lam             = (const float*)d_in[7];
    float* out = (float*)d_out;

    float* wsf = (float*)d_ws;
    int*   wsi = (int*)d_ws;
    int*   counter  = wsi + WS_COUNTER;
    int*   meta_c   = wsi + WS_META_C;
    int*   meta_out = wsi + WS_META_O;
    float* f_irng   = wsf + WS_IRNG;
    float* f_gmax   = wsf + WS_GMAX;
    float* f_scale  = wsf + WS_SCALE;
    float* cn       = wsf + WS_CN;
    float* cos_bv   = wsf + WS_COS;
    float* mean_j   = wsf + WS_MEANJ;

    hipMemsetAsync(out, 0, (size_t)out_size * sizeof(float), stream);
    hipMemsetAsync(counter, 0, 64, stream);

    k_mean<<<NB * NS, ND, 0, stream>>>(concepts, concepts_length, embed_w, mean_j);
    k_ctx2<<<NB, ND, 0, stream>>>(seg_len, mean_j, cn);
    k_cos<<<NV / 8, 256, 0, stream>>>(embed_kb_w, cn, cos_bv);
    k_A<<<MAXSLOTS, 256, 0, stream>>>(concepts, concepts_length, seg_len,
                                      edge_matrix, affectiveness, lam, cos_bv,
                                      counter, meta_c, meta_out,
                                      f_irng, f_gmax, f_scale);
    dim3 gB(MAXSLOTS / TROWS, USPLIT, 1);
    k_B<<<gB, 256, 0, stream>>>(edge_matrix, affectiveness, lam, embed_kb_w,
                                cos_bv, counter, meta_c, meta_out,
                                f_irng, f_gmax, f_scale, out);
}